// Round 1
// baseline (1338.778 us; speedup 1.0000x reference)
//
#include <hip/hip_runtime.h>
#include <hip/hip_bf16.h>
#include <math.h>

#define NNODES 50000
#define HID    64
#define HEADS  4
#define FDIM   256   // HEADS*HID

__device__ __forceinline__ float lrelu(float x) { return x > 0.f ? x : 0.2f * x; }

// ---------------- GEMM: Y[M,N] = X[M,K] @ W[K,N] (+bias) (+relu) ----------------
// block = 256 threads; CG = 256/N column groups; R = RPT*CG rows per block.
template<int K, int N, int RPT, bool RELU>
__global__ __launch_bounds__(256) void gemm_kernel(
    const float* __restrict__ X, const float* __restrict__ W,
    const float* __restrict__ B, float* __restrict__ Y, int M)
{
  static_assert(256 % N == 0, "N must divide 256");
  constexpr int CG = 256 / N;
  constexpr int R  = RPT * CG;
  __shared__ float xs[R * K];
  const int tid  = threadIdx.x;
  const int row0 = blockIdx.x * R;
  for (int i = tid; i < R * K; i += 256) {
    int r = i / K, k = i - r * K;
    int gr = row0 + r;
    xs[i] = (gr < M) ? X[(size_t)gr * K + k] : 0.f;
  }
  __syncthreads();
  const int c = tid % N;
  const int g = tid / N;
  float acc[RPT];
#pragma unroll
  for (int r = 0; r < RPT; ++r) acc[r] = 0.f;
  for (int k0 = 0; k0 < K; k0 += 4) {
    float w0 = W[(size_t)(k0 + 0) * N + c];
    float w1 = W[(size_t)(k0 + 1) * N + c];
    float w2 = W[(size_t)(k0 + 2) * N + c];
    float w3 = W[(size_t)(k0 + 3) * N + c];
#pragma unroll
    for (int r = 0; r < RPT; ++r) {
      const float4 xv = *reinterpret_cast<const float4*>(&xs[(g * RPT + r) * K + k0]);
      acc[r] = fmaf(xv.x, w0, acc[r]);
      acc[r] = fmaf(xv.y, w1, acc[r]);
      acc[r] = fmaf(xv.z, w2, acc[r]);
      acc[r] = fmaf(xv.w, w3, acc[r]);
    }
  }
#pragma unroll
  for (int r = 0; r < RPT; ++r) {
    int gr = row0 + g * RPT + r;
    if (gr < M) {
      float val = acc[r] + (B ? B[c] : 0.f);
      if (RELU) val = fmaxf(val, 0.f);
      Y[(size_t)gr * N + c] = val;
    }
  }
}

// ---------------- CSR build ----------------
__global__ void hist_kernel(const int* __restrict__ dst, int* __restrict__ deg, int E)
{
  int i = blockIdx.x * blockDim.x + threadIdx.x;
  if (i < E) atomicAdd(&deg[dst[i]], 1);
}

// single-block exclusive scan (n up to ~64K); block = 1024 threads
__global__ __launch_bounds__(1024) void exscan_kernel(const int* __restrict__ deg,
                                                      int* __restrict__ off, int n)
{
  __shared__ int wsum[16];
  __shared__ int carry_s;
  const int t = threadIdx.x, lane = t & 63, w = t >> 6;
  if (t == 0) carry_s = 0;
  __syncthreads();
  for (int base = 0; base < n; base += 1024) {
    int i = base + t;
    int v = (i < n) ? deg[i] : 0;
    int x = v;
#pragma unroll
    for (int d = 1; d < 64; d <<= 1) {
      int y = __shfl_up(x, d, 64);
      if (lane >= d) x += y;
    }
    if (lane == 63) wsum[w] = x;
    __syncthreads();
    if (w == 0) {
      int s = (lane < 16) ? wsum[lane] : 0;
#pragma unroll
      for (int d = 1; d < 16; d <<= 1) {
        int y = __shfl_up(s, d, 64);
        if (lane >= d) s += y;
      }
      if (lane < 16) wsum[lane] = s;
    }
    __syncthreads();
    int wpre = (w > 0) ? wsum[w - 1] : 0;
    int incl = carry_s + wpre + x;
    if (i < n) off[i] = incl - v;
    __syncthreads();
    if (t == 1023) carry_s = incl;
    __syncthreads();
  }
  if (t == 0) off[n] = carry_s;
}

__global__ void scatter_kernel(const int* __restrict__ dst, const int* __restrict__ off,
                               int* __restrict__ cursor, int* __restrict__ eid, int E)
{
  int i = blockIdx.x * blockDim.x + threadIdx.x;
  if (i < E) {
    int d = dst[i];
    int p = atomicAdd(&cursor[d], 1);
    eid[off[d] + p] = i;
  }
}

// ---------------- per-node attention logits: a_s/a_d [N, HEADS] ----------------
__global__ void logits_kernel(const float* __restrict__ hW, const float* __restrict__ att_s,
                              const float* __restrict__ att_d, float* __restrict__ a_s,
                              float* __restrict__ a_d, int n_nodes)
{
  int t = blockIdx.x * blockDim.x + threadIdx.x;
  if (t >= n_nodes * HEADS) return;
  int n = t >> 2, h = t & 3;
  const float* hp = hW + (size_t)n * FDIM + h * HID;
  const float* ws = att_s + h * HID;
  const float* wd = att_d + h * HID;
  float as = 0.f, ad = 0.f;
#pragma unroll 4
  for (int k = 0; k < HID; ++k) {
    float xv = hp[k];
    as = fmaf(xv, ws[k], as);
    ad = fmaf(xv, wd[k], ad);
  }
  a_s[t] = as;
  a_d[t] = ad;
}

// ---------------- GAT aggregation: one wave per dst node ----------------
__global__ __launch_bounds__(256) void aggregate_kernel(
    const float* __restrict__ hW, const float* __restrict__ a_s, const float* __restrict__ a_d,
    const int* __restrict__ off, const int* __restrict__ eid, const int* __restrict__ srcv,
    const float* __restrict__ bias, float* __restrict__ out, int n_nodes)
{
  const int wid  = (blockIdx.x * 256 + threadIdx.x) >> 6;
  const int lane = threadIdx.x & 63;
  if (wid >= n_nodes) return;
  const int n = wid;
  const int beg = off[n], end = off[n + 1];
  const float ad0 = a_d[n * 4 + 0], ad1 = a_d[n * 4 + 1];
  const float ad2 = a_d[n * 4 + 2], ad3 = a_d[n * 4 + 3];
  float m0 = -INFINITY, m1 = -INFINITY, m2 = -INFINITY, m3 = -INFINITY;
  for (int i = beg; i < end; ++i) {
    int s = srcv[eid[i]];
    m0 = fmaxf(m0, lrelu(a_s[s * 4 + 0] + ad0));
    m1 = fmaxf(m1, lrelu(a_s[s * 4 + 1] + ad1));
    m2 = fmaxf(m2, lrelu(a_s[s * 4 + 2] + ad2));
    m3 = fmaxf(m3, lrelu(a_s[s * 4 + 3] + ad3));
  }
  float s0 = 0.f, s1 = 0.f, s2 = 0.f, s3 = 0.f;
  float acc0 = 0.f, acc1 = 0.f, acc2 = 0.f, acc3 = 0.f;
  for (int i = beg; i < end; ++i) {
    int s = srcv[eid[i]];
    float w0 = __expf(lrelu(a_s[s * 4 + 0] + ad0) - m0);
    float w1 = __expf(lrelu(a_s[s * 4 + 1] + ad1) - m1);
    float w2 = __expf(lrelu(a_s[s * 4 + 2] + ad2) - m2);
    float w3 = __expf(lrelu(a_s[s * 4 + 3] + ad3) - m3);
    s0 += w0; s1 += w1; s2 += w2; s3 += w3;
    const float* hp = hW + (size_t)s * FDIM;
    acc0 = fmaf(w0, hp[lane], acc0);
    acc1 = fmaf(w1, hp[64 + lane], acc1);
    acc2 = fmaf(w2, hp[128 + lane], acc2);
    acc3 = fmaf(w3, hp[192 + lane], acc3);
  }
  float* op = out + (size_t)n * FDIM;
  op[lane]       = acc0 / (s0 + 1e-16f) + bias[lane];
  op[64 + lane]  = acc1 / (s1 + 1e-16f) + bias[64 + lane];
  op[128 + lane] = acc2 / (s2 + 1e-16f) + bias[128 + lane];
  op[192 + lane] = acc3 / (s3 + 1e-16f) + bias[192 + lane];
}

// ---------------- link predictor: one wave per eval pair ----------------
__global__ __launch_bounds__(256) void linkpred_kernel(
    const float* __restrict__ u, const float* __restrict__ v,
    const int* __restrict__ es, const int* __restrict__ ed,
    const float* __restrict__ b1, const float* __restrict__ w2, const float* __restrict__ b2,
    const float* __restrict__ w3, const float* __restrict__ b3,
    float* __restrict__ out, int n_eval)
{
  __shared__ float w2s[64 * 32];
  __shared__ float z1s[4][64];
  __shared__ float z2s[4][32];
  const int t = threadIdx.x;
  for (int i = t; i < 64 * 32; i += 256) w2s[i] = w2[i];
  const int wid = t >> 6, lane = t & 63;
  const int pair = blockIdx.x * 4 + wid;
  const bool valid = pair < n_eval;
  const int pc = valid ? pair : (n_eval - 1);
  const int s = es[pc], d = ed[pc];
  float z1 = fmaxf(u[(size_t)s * 64 + lane] + v[(size_t)d * 64 + lane] + b1[lane], 0.f);
  z1s[wid][lane] = z1;
  __syncthreads();
  if (lane < 32) {
    float acc = b2[lane];
#pragma unroll
    for (int k = 0; k < 64; ++k) acc = fmaf(z1s[wid][k], w2s[k * 32 + lane], acc);
    z2s[wid][lane] = fmaxf(acc, 0.f);
  }
  __syncthreads();
  if (lane == 0 && valid) {
    float acc = b3[0];
#pragma unroll
    for (int k = 0; k < 32; ++k) acc = fmaf(z2s[wid][k], w3[k], acc);
    out[pair] = acc;
  }
}

// ---------------- launch ----------------
extern "C" void kernel_launch(void* const* d_in, const int* in_sizes, int n_in,
                              void* d_out, int out_size, void* d_ws, size_t ws_size,
                              hipStream_t stream)
{
  const float* x     = (const float*)d_in[0];
  const int*   ei    = (const int*)d_in[1];
  const int*   esrc  = (const int*)d_in[2];
  const int*   edst  = (const int*)d_in[3];
  const float* enc_w = (const float*)d_in[4];
  const float* enc_b = (const float*)d_in[5];
  const float* g1_w  = (const float*)d_in[6];
  const float* g1_as = (const float*)d_in[7];
  const float* g1_ad = (const float*)d_in[8];
  const float* g1_b  = (const float*)d_in[9];
  const float* g2_w  = (const float*)d_in[10];
  const float* g2_as = (const float*)d_in[11];
  const float* g2_ad = (const float*)d_in[12];
  const float* g2_b  = (const float*)d_in[13];
  const float* lp1_w = (const float*)d_in[14];
  const float* lp1_b = (const float*)d_in[15];
  const float* lp2_w = (const float*)d_in[16];
  const float* lp2_b = (const float*)d_in[17];
  const float* lp3_w = (const float*)d_in[18];
  const float* lp3_b = (const float*)d_in[19];
  float* out = (float*)d_out;

  const int E  = in_sizes[1] / 2;   // 1,000,000
  const int NE = in_sizes[2];       // 100,000
  const int M  = NNODES;

  const int* e_src = ei;
  const int* e_dst = ei + E;

  // ---- workspace layout (≈121 MB) ----
  float* h_enc = (float*)d_ws;                       // M*64
  float* hW    = h_enc + (size_t)M * HID;            // M*256
  float* aggA  = hW + (size_t)M * FDIM;              // M*256
  float* a_s   = aggA + (size_t)M * FDIM;            // M*4
  float* a_d   = a_s + (size_t)M * HEADS;            // M*4
  int*   deg    = (int*)(a_d + (size_t)M * HEADS);   // M
  int*   cursor = deg + M;                           // M
  int*   off    = cursor + M;                        // M+1
  int*   eid    = off + M + 1;                       // E
  float* u = hW;                                     // reused after GAT2 aggregate
  float* v = hW + (size_t)M * HID;

  // ---- CSR build (same edges both layers) ----
  hipMemsetAsync(deg, 0, sizeof(int) * 2 * (size_t)M, stream);
  hist_kernel<<<(E + 255) / 256, 256, 0, stream>>>(e_dst, deg, E);
  exscan_kernel<<<1, 1024, 0, stream>>>(deg, off, M);
  scatter_kernel<<<(E + 255) / 256, 256, 0, stream>>>(e_dst, off, cursor, eid, E);

  // ---- encoder: h_enc = relu(x @ enc_w + enc_b) ----
  gemm_kernel<256, 64, 4, true><<<(M + 15) / 16, 256, 0, stream>>>(x, enc_w, enc_b, h_enc, M);

  // ---- GAT layer 1 ----
  gemm_kernel<64, 256, 16, false><<<(M + 15) / 16, 256, 0, stream>>>(h_enc, g1_w, nullptr, hW, M);
  logits_kernel<<<(M * HEADS + 255) / 256, 256, 0, stream>>>(hW, g1_as, g1_ad, a_s, a_d, M);
  aggregate_kernel<<<(M * 64 + 255) / 256, 256, 0, stream>>>(hW, a_s, a_d, off, eid, e_src, g1_b, aggA, M);

  // ---- GAT layer 2 ----
  gemm_kernel<256, 256, 16, false><<<(M + 15) / 16, 256, 0, stream>>>(aggA, g2_w, nullptr, hW, M);
  logits_kernel<<<(M * HEADS + 255) / 256, 256, 0, stream>>>(hW, g2_as, g2_ad, a_s, a_d, M);
  aggregate_kernel<<<(M * 64 + 255) / 256, 256, 0, stream>>>(hW, a_s, a_d, off, eid, e_src, g2_b, aggA, M);

  // ---- link predictor: u/v precompute + fused pair MLP ----
  gemm_kernel<256, 64, 4, false><<<(M + 15) / 16, 256, 0, stream>>>(aggA, lp1_w, nullptr, u, M);
  gemm_kernel<256, 64, 4, false><<<(M + 15) / 16, 256, 0, stream>>>(aggA, lp1_w + 256 * 64, nullptr, v, M);
  linkpred_kernel<<<(NE + 3) / 4, 256, 0, stream>>>(u, v, esrc, edst, lp1_b, lp2_w, lp2_b,
                                                    lp3_w, lp3_b, out, NE);
}

// Round 2
// 1014.690 us; speedup vs baseline: 1.3194x; 1.3194x over previous
//
#include <hip/hip_runtime.h>
#include <hip/hip_bf16.h>
#include <math.h>

#define NNODES 50000
#define HID    64
#define HEADS  4
#define FDIM   256   // HEADS*HID

__device__ __forceinline__ float lrelu(float x) { return x > 0.f ? x : 0.2f * x; }

// ---------------- GEMM: Y[M,N] = X[M,K] @ W[K,N] (+bias) (+relu) ----------------
template<int K, int N, int RPT, bool RELU>
__global__ __launch_bounds__(256) void gemm_kernel(
    const float* __restrict__ X, const float* __restrict__ W,
    const float* __restrict__ B, float* __restrict__ Y, int M)
{
  static_assert(256 % N == 0, "N must divide 256");
  constexpr int CG = 256 / N;
  constexpr int R  = RPT * CG;
  __shared__ float xs[R * K];
  const int tid  = threadIdx.x;
  const int row0 = blockIdx.x * R;
  for (int i = tid; i < R * K; i += 256) {
    int r = i / K, k = i - r * K;
    int gr = row0 + r;
    xs[i] = (gr < M) ? X[(size_t)gr * K + k] : 0.f;
  }
  __syncthreads();
  const int c = tid % N;
  const int g = tid / N;
  float acc[RPT];
#pragma unroll
  for (int r = 0; r < RPT; ++r) acc[r] = 0.f;
  for (int k0 = 0; k0 < K; k0 += 4) {
    float w0 = W[(size_t)(k0 + 0) * N + c];
    float w1 = W[(size_t)(k0 + 1) * N + c];
    float w2 = W[(size_t)(k0 + 2) * N + c];
    float w3 = W[(size_t)(k0 + 3) * N + c];
#pragma unroll
    for (int r = 0; r < RPT; ++r) {
      const float4 xv = *reinterpret_cast<const float4*>(&xs[(g * RPT + r) * K + k0]);
      acc[r] = fmaf(xv.x, w0, acc[r]);
      acc[r] = fmaf(xv.y, w1, acc[r]);
      acc[r] = fmaf(xv.z, w2, acc[r]);
      acc[r] = fmaf(xv.w, w3, acc[r]);
    }
  }
#pragma unroll
  for (int r = 0; r < RPT; ++r) {
    int gr = row0 + g * RPT + r;
    if (gr < M) {
      float val = acc[r] + (B ? B[c] : 0.f);
      if (RELU) val = fmaxf(val, 0.f);
      Y[(size_t)gr * N + c] = val;
    }
  }
}

// ---------------- CSR build ----------------
__global__ void hist_kernel(const int* __restrict__ dst, int* __restrict__ deg, int E)
{
  int i = blockIdx.x * blockDim.x + threadIdx.x;
  if (i < E) atomicAdd(&deg[dst[i]], 1);
}

__global__ __launch_bounds__(1024) void exscan_kernel(const int* __restrict__ deg,
                                                      int* __restrict__ off, int n)
{
  __shared__ int wsum[16];
  __shared__ int carry_s;
  const int t = threadIdx.x, lane = t & 63, w = t >> 6;
  if (t == 0) carry_s = 0;
  __syncthreads();
  for (int base = 0; base < n; base += 1024) {
    int i = base + t;
    int v = (i < n) ? deg[i] : 0;
    int x = v;
#pragma unroll
    for (int d = 1; d < 64; d <<= 1) {
      int y = __shfl_up(x, d, 64);
      if (lane >= d) x += y;
    }
    if (lane == 63) wsum[w] = x;
    __syncthreads();
    if (w == 0) {
      int s = (lane < 16) ? wsum[lane] : 0;
#pragma unroll
      for (int d = 1; d < 16; d <<= 1) {
        int y = __shfl_up(s, d, 64);
        if (lane >= d) s += y;
      }
      if (lane < 16) wsum[lane] = s;
    }
    __syncthreads();
    int wpre = (w > 0) ? wsum[w - 1] : 0;
    int incl = carry_s + wpre + x;
    if (i < n) off[i] = incl - v;
    __syncthreads();
    if (t == 1023) carry_s = incl;
    __syncthreads();
  }
  if (t == 0) off[n] = carry_s;
}

// scatter: store src node id per CSR slot + remember each edge's slot
__global__ void scatter_kernel(const int* __restrict__ src, const int* __restrict__ dst,
                               const int* __restrict__ off, int* __restrict__ cursor,
                               int* __restrict__ sidx, int* __restrict__ slotOf, int E)
{
  int i = blockIdx.x * blockDim.x + threadIdx.x;
  if (i < E) {
    int d = dst[i];
    int p = atomicAdd(&cursor[d], 1);
    int slot = off[d] + p;
    sidx[slot] = src[i];
    slotOf[i] = slot;
  }
}

// ---------------- per-node attention logits: a_s/a_d [N, HEADS] ----------------
__global__ void logits_kernel(const float* __restrict__ hW, const float* __restrict__ att_s,
                              const float* __restrict__ att_d, float* __restrict__ a_s,
                              float* __restrict__ a_d, int n_nodes)
{
  int t = blockIdx.x * blockDim.x + threadIdx.x;
  if (t >= n_nodes * HEADS) return;
  int n = t >> 2, h = t & 3;
  const float* hp = hW + (size_t)n * FDIM + h * HID;
  const float* ws = att_s + h * HID;
  const float* wd = att_d + h * HID;
  float as = 0.f, ad = 0.f;
#pragma unroll 4
  for (int k = 0; k < HID; ++k) {
    float xv = hp[k];
    as = fmaf(xv, ws[k], as);
    ad = fmaf(xv, wd[k], ad);
  }
  a_s[t] = as;
  a_d[t] = ad;
}

// ---------------- per-edge logits into CSR order: elog[slot][4] ----------------
__global__ void elog_kernel(const int* __restrict__ src, const int* __restrict__ dst,
                            const int* __restrict__ slotOf,
                            const float* __restrict__ a_s, const float* __restrict__ a_d,
                            float4* __restrict__ elog, int E)
{
  int i = blockIdx.x * blockDim.x + threadIdx.x;
  if (i >= E) return;
  const float4 as = *reinterpret_cast<const float4*>(a_s + (size_t)src[i] * 4);
  const float4 ad = *reinterpret_cast<const float4*>(a_d + (size_t)dst[i] * 4);
  float4 e;
  e.x = lrelu(as.x + ad.x);
  e.y = lrelu(as.y + ad.y);
  e.z = lrelu(as.z + ad.z);
  e.w = lrelu(as.w + ad.w);
  elog[slotOf[i]] = e;
}

// ---------------- GAT aggregation v2: one wave per dst node ----------------
// Phase A (lane-parallel over edges): per-head max, exp, store w back, per-head sum.
// Phase B (edge loop, high ILP): uniform w + src loads, coalesced hW reads.
__global__ __launch_bounds__(256) void aggregate_kernel(
    const float* __restrict__ hW, float* __restrict__ elog, const int* __restrict__ sidx,
    const int* __restrict__ off, const float* __restrict__ bias,
    float* __restrict__ out, int n_nodes)
{
  const int wid  = (blockIdx.x * 256 + threadIdx.x) >> 6;
  const int lane = threadIdx.x & 63;
  if (wid >= n_nodes) return;
  const int n = wid;
  const int beg = off[n], end = off[n + 1];

  // ---- Phase A: per-head softmax stats over elog[beg*4 .. end*4) ----
  // lane i covers flat positions beg*4+i, +64, ... ; its head class = lane&3.
  float m = -INFINITY;
  for (int p = beg * 4 + lane; p < end * 4; p += 64) m = fmaxf(m, elog[p]);
#pragma unroll
  for (int d = 4; d < 64; d <<= 1) m = fmaxf(m, __shfl_xor(m, d, 64));
  float ssum = 0.f;
  for (int p = beg * 4 + lane; p < end * 4; p += 64) {
    float w = __expf(elog[p] - m);
    elog[p] = w;
    ssum += w;
  }
#pragma unroll
  for (int d = 4; d < 64; d <<= 1) ssum += __shfl_xor(ssum, d, 64);
  const float s0 = __shfl(ssum, 0, 64), s1 = __shfl(ssum, 1, 64);
  const float s2 = __shfl(ssum, 2, 64), s3 = __shfl(ssum, 3, 64);

  // ---- Phase B: weighted accumulate over edges ----
  float acc0 = 0.f, acc1 = 0.f, acc2 = 0.f, acc3 = 0.f;
  const float4* wv = reinterpret_cast<const float4*>(elog);
#pragma unroll 4
  for (int j = beg; j < end; ++j) {
    const int s = sidx[j];                 // uniform 4B load
    const float4 w = wv[j];                // uniform 16B load (just written)
    const float* hp = hW + (size_t)s * FDIM;
    acc0 = fmaf(w.x, hp[lane], acc0);
    acc1 = fmaf(w.y, hp[64 + lane], acc1);
    acc2 = fmaf(w.z, hp[128 + lane], acc2);
    acc3 = fmaf(w.w, hp[192 + lane], acc3);
  }
  float* op = out + (size_t)n * FDIM;
  op[lane]       = acc0 / (s0 + 1e-16f) + bias[lane];
  op[64 + lane]  = acc1 / (s1 + 1e-16f) + bias[64 + lane];
  op[128 + lane] = acc2 / (s2 + 1e-16f) + bias[128 + lane];
  op[192 + lane] = acc3 / (s3 + 1e-16f) + bias[192 + lane];
}

// ---------------- link predictor: one wave per eval pair ----------------
__global__ __launch_bounds__(256) void linkpred_kernel(
    const float* __restrict__ u, const float* __restrict__ v,
    const int* __restrict__ es, const int* __restrict__ ed,
    const float* __restrict__ b1, const float* __restrict__ w2, const float* __restrict__ b2,
    const float* __restrict__ w3, const float* __restrict__ b3,
    float* __restrict__ out, int n_eval)
{
  __shared__ float w2s[64 * 32];
  __shared__ float z1s[4][64];
  __shared__ float z2s[4][32];
  const int t = threadIdx.x;
  for (int i = t; i < 64 * 32; i += 256) w2s[i] = w2[i];
  const int wid = t >> 6, lane = t & 63;
  const int pair = blockIdx.x * 4 + wid;
  const bool valid = pair < n_eval;
  const int pc = valid ? pair : (n_eval - 1);
  const int s = es[pc], d = ed[pc];
  float z1 = fmaxf(u[(size_t)s * 64 + lane] + v[(size_t)d * 64 + lane] + b1[lane], 0.f);
  z1s[wid][lane] = z1;
  __syncthreads();
  if (lane < 32) {
    float acc = b2[lane];
#pragma unroll
    for (int k = 0; k < 64; ++k) acc = fmaf(z1s[wid][k], w2s[k * 32 + lane], acc);
    z2s[wid][lane] = fmaxf(acc, 0.f);
  }
  __syncthreads();
  if (lane == 0 && valid) {
    float acc = b3[0];
#pragma unroll
    for (int k = 0; k < 32; ++k) acc = fmaf(z2s[wid][k], w3[k], acc);
    out[pair] = acc;
  }
}

// ---------------- launch ----------------
extern "C" void kernel_launch(void* const* d_in, const int* in_sizes, int n_in,
                              void* d_out, int out_size, void* d_ws, size_t ws_size,
                              hipStream_t stream)
{
  const float* x     = (const float*)d_in[0];
  const int*   ei    = (const int*)d_in[1];
  const int*   esrc  = (const int*)d_in[2];
  const int*   edst  = (const int*)d_in[3];
  const float* enc_w = (const float*)d_in[4];
  const float* enc_b = (const float*)d_in[5];
  const float* g1_w  = (const float*)d_in[6];
  const float* g1_as = (const float*)d_in[7];
  const float* g1_ad = (const float*)d_in[8];
  const float* g1_b  = (const float*)d_in[9];
  const float* g2_w  = (const float*)d_in[10];
  const float* g2_as = (const float*)d_in[11];
  const float* g2_ad = (const float*)d_in[12];
  const float* g2_b  = (const float*)d_in[13];
  const float* lp1_w = (const float*)d_in[14];
  const float* lp1_b = (const float*)d_in[15];
  const float* lp2_w = (const float*)d_in[16];
  const float* lp2_b = (const float*)d_in[17];
  const float* lp3_w = (const float*)d_in[18];
  const float* lp3_b = (const float*)d_in[19];
  float* out = (float*)d_out;

  const int E  = in_sizes[1] / 2;   // 1,000,000
  const int NE = in_sizes[2];       // 100,000
  const int M  = NNODES;

  const int* e_src = ei;
  const int* e_dst = ei + E;

  // ---- workspace layout (floats then ints, all 16B aligned) ----
  float* h_enc = (float*)d_ws;                       // M*64   = 3.2M f
  float* hW    = h_enc + (size_t)M * HID;            // M*256  = 12.8M f
  float* aggA  = hW + (size_t)M * FDIM;              // M*256
  float* a_s   = aggA + (size_t)M * FDIM;            // M*4
  float* a_d   = a_s + (size_t)M * HEADS;            // M*4
  float* elog  = a_d + (size_t)M * HEADS;            // E*4    = 4M f
  int*   deg    = (int*)(elog + (size_t)E * 4);      // M
  int*   cursor = deg + M;                           // M
  int*   off    = cursor + M;                        // M+1
  int*   sidx   = off + M + 1;                       // E
  int*   slotOf = sidx + E;                          // E
  float* u = hW;                                     // reused after GAT2 aggregate
  float* v = hW + (size_t)M * HID;

  // ---- CSR build ----
  hipMemsetAsync(deg, 0, sizeof(int) * 2 * (size_t)M, stream);
  hist_kernel<<<(E + 255) / 256, 256, 0, stream>>>(e_dst, deg, E);
  exscan_kernel<<<1, 1024, 0, stream>>>(deg, off, M);
  scatter_kernel<<<(E + 255) / 256, 256, 0, stream>>>(e_src, e_dst, off, cursor, sidx, slotOf, E);

  // ---- encoder ----
  gemm_kernel<256, 64, 4, true><<<(M + 15) / 16, 256, 0, stream>>>(x, enc_w, enc_b, h_enc, M);

  // ---- GAT layer 1 ----
  gemm_kernel<64, 256, 16, false><<<(M + 15) / 16, 256, 0, stream>>>(h_enc, g1_w, nullptr, hW, M);
  logits_kernel<<<(M * HEADS + 255) / 256, 256, 0, stream>>>(hW, g1_as, g1_ad, a_s, a_d, M);
  elog_kernel<<<(E + 255) / 256, 256, 0, stream>>>(e_src, e_dst, slotOf, a_s, a_d, (float4*)elog, E);
  aggregate_kernel<<<(M * 64 + 255) / 256, 256, 0, stream>>>(hW, elog, sidx, off, g1_b, aggA, M);

  // ---- GAT layer 2 ----
  gemm_kernel<256, 256, 16, false><<<(M + 15) / 16, 256, 0, stream>>>(aggA, g2_w, nullptr, hW, M);
  logits_kernel<<<(M * HEADS + 255) / 256, 256, 0, stream>>>(hW, g2_as, g2_ad, a_s, a_d, M);
  elog_kernel<<<(E + 255) / 256, 256, 0, stream>>>(e_src, e_dst, slotOf, a_s, a_d, (float4*)elog, E);
  aggregate_kernel<<<(M * 64 + 255) / 256, 256, 0, stream>>>(hW, elog, sidx, off, g2_b, aggA, M);

  // ---- link predictor ----
  gemm_kernel<256, 64, 4, false><<<(M + 15) / 16, 256, 0, stream>>>(aggA, lp1_w, nullptr, u, M);
  gemm_kernel<256, 64, 4, false><<<(M + 15) / 16, 256, 0, stream>>>(aggA, lp1_w + 256 * 64, nullptr, v, M);
  linkpred_kernel<<<(NE + 3) / 4, 256, 0, stream>>>(u, v, esrc, edst, lp1_b, lp2_w, lp2_b,
                                                    lp3_w, lp3_b, out, NE);
}

// Round 3
// 894.428 us; speedup vs baseline: 1.4968x; 1.1345x over previous
//
#include <hip/hip_runtime.h>
#include <hip/hip_bf16.h>
#include <math.h>

#define NNODES 50000
#define HID    64
#define HEADS  4
#define FDIM   256   // HEADS*HID

typedef __attribute__((ext_vector_type(8))) short short8v;
typedef __attribute__((ext_vector_type(4))) float f32x4;

__device__ __forceinline__ float lrelu(float x) { return x > 0.f ? x : 0.2f * x; }

__device__ __forceinline__ ushort f2bf(float x) {
  union { float f; unsigned u; } c; c.f = x;
  unsigned r = (c.u + 0x7FFF + ((c.u >> 16) & 1)) >> 16;   // RNE
  return (ushort)r;
}
__device__ __forceinline__ float bf2f(ushort h) {
  union { unsigned u; float f; } c; c.u = ((unsigned)h) << 16;
  return c.f;
}

// ---------------- f32 -> (hi,lo) bf16 split, vectorized ----------------
__global__ void split_kernel(const float4* __restrict__ x, ushort* __restrict__ hi,
                             ushort* __restrict__ lo, int n4)
{
  int t = blockIdx.x * blockDim.x + threadIdx.x;
  if (t >= n4) return;
  float4 v = x[t];
  ushort h0 = f2bf(v.x), h1 = f2bf(v.y), h2 = f2bf(v.z), h3 = f2bf(v.w);
  *(ushort4*)(hi + (size_t)t * 4) = make_ushort4(h0, h1, h2, h3);
  *(ushort4*)(lo + (size_t)t * 4) = make_ushort4(
      f2bf(v.x - bf2f(h0)), f2bf(v.y - bf2f(h1)),
      f2bf(v.z - bf2f(h2)), f2bf(v.w - bf2f(h3)));
}

// ---------------- W[K][N] f32 -> Wt_hi/Wt_lo [N][K] bf16 ----------------
__global__ void wtconv_kernel(const float* __restrict__ W, ushort* __restrict__ Whi,
                              ushort* __restrict__ Wlo, int K, int N)
{
  int t = blockIdx.x * blockDim.x + threadIdx.x;
  if (t >= K * N) return;
  int n = t / K, k = t - n * K;
  float w = W[(size_t)k * N + n];
  ushort h = f2bf(w);
  Whi[t] = h;
  Wlo[t] = f2bf(w - bf2f(h));
}

// ---------------- MFMA GEMM: C[M,Ntot] = A[M,KTOT] @ B, 3-pass bf16 ----------------
// A: hi/lo bf16 planes, row-major, staged to LDS via global_load_lds (pre-swizzled src).
// B: Wt hi/lo planes [Ntot][KTOT], fragments read directly from global (L1/L2-resident).
// OUTMODE 0: f32 out. OUTMODE 1: bias + relu + split bf16 out (row-major [M][Ntot]).
template<int KTOT, int OUTMODE>
__global__ __launch_bounds__(256) void mfma_gemm(
    const ushort* __restrict__ Ahi, const ushort* __restrict__ Alo,
    const ushort* __restrict__ Bhi, const ushort* __restrict__ Blo,
    const float* __restrict__ bias,
    float* __restrict__ outF, ushort* __restrict__ outHi, ushort* __restrict__ outLo,
    int M, int Ntot)
{
  __shared__ ushort AsH[128 * 64];
  __shared__ ushort AsL[128 * 64];
  const int tid  = threadIdx.x;
  const int lane = tid & 63;
  const int wid  = tid >> 6;
  const int row0 = blockIdx.x * 128;
  const int col0 = blockIdx.y * 64;

  f32x4 acc[2][4];
#pragma unroll
  for (int m = 0; m < 2; ++m)
#pragma unroll
    for (int n = 0; n < 4; ++n) acc[m][n] = (f32x4){0.f, 0.f, 0.f, 0.f};

  const int rsub = lane >> 3;   // row within 8-row chunk
  const int slot = lane & 7;    // 16B slot within 128B LDS row
  const int brow = col0 + (lane & 15);
  const int bk   = (lane >> 4) * 8;

  for (int kt = 0; kt < KTOT; kt += 64) {
    // ---- stage A tile (hi+lo): 16 chunks of 8 rows x 128B, swizzled source ----
#pragma unroll
    for (int i = 0; i < 4; ++i) {
      const int c  = i * 4 + wid;
      const int r  = c * 8 + rsub;
      const int gr = min(row0 + r, M - 1);
      const int ss = slot ^ rsub;                       // involution swizzle (T2)
      const size_t goff = (size_t)gr * KTOT + kt + ss * 8;
      __builtin_amdgcn_global_load_lds(
          (const __attribute__((address_space(1))) void*)(Ahi + goff),
          (__attribute__((address_space(3))) void*)(AsH + c * 512), 16, 0, 0);
      __builtin_amdgcn_global_load_lds(
          (const __attribute__((address_space(1))) void*)(Alo + goff),
          (__attribute__((address_space(3))) void*)(AsL + c * 512), 16, 0, 0);
    }
    __syncthreads();

#pragma unroll
    for (int ks = 0; ks < 2; ++ks) {
      short8v ah[2], al[2], bh[4], bl[4];
#pragma unroll
      for (int mf = 0; mf < 2; ++mf) {
        const int r   = wid * 32 + mf * 16 + (lane & 15);
        const int sl  = (ks * 4 + (lane >> 4)) ^ (r & 7);
        const int idx = r * 64 + sl * 8;
        ah[mf] = *(const short8v*)(AsH + idx);
        al[mf] = *(const short8v*)(AsL + idx);
      }
#pragma unroll
      for (int nf = 0; nf < 4; ++nf) {
        const size_t bo = (size_t)(brow + nf * 16) * KTOT + kt + ks * 32 + bk;
        bh[nf] = *(const short8v*)(Bhi + bo);
        bl[nf] = *(const short8v*)(Blo + bo);
      }
#pragma unroll
      for (int mf = 0; mf < 2; ++mf)
#pragma unroll
        for (int nf = 0; nf < 4; ++nf) {
          acc[mf][nf] = __builtin_amdgcn_mfma_f32_16x16x32_bf16(ah[mf], bh[nf], acc[mf][nf], 0, 0, 0);
          acc[mf][nf] = __builtin_amdgcn_mfma_f32_16x16x32_bf16(al[mf], bh[nf], acc[mf][nf], 0, 0, 0);
          acc[mf][nf] = __builtin_amdgcn_mfma_f32_16x16x32_bf16(ah[mf], bl[nf], acc[mf][nf], 0, 0, 0);
        }
    }
    __syncthreads();
  }

  // ---- epilogue: C/D frag layout col=lane&15, row=(lane>>4)*4+reg ----
  const int crow = row0 + wid * 32 + (lane >> 4) * 4;
  const int ccol = col0 + (lane & 15);
#pragma unroll
  for (int mf = 0; mf < 2; ++mf)
#pragma unroll
    for (int nf = 0; nf < 4; ++nf)
#pragma unroll
      for (int r = 0; r < 4; ++r) {
        const int grow = crow + mf * 16 + r;
        const int gcol = ccol + nf * 16;
        if (grow < M) {
          float v = acc[mf][nf][r];
          if (OUTMODE == 1) {
            v = fmaxf(v + bias[gcol], 0.f);
            const ushort h = f2bf(v);
            outHi[(size_t)grow * Ntot + gcol] = h;
            outLo[(size_t)grow * Ntot + gcol] = f2bf(v - bf2f(h));
          } else {
            outF[(size_t)grow * Ntot + gcol] = v;
          }
        }
      }
}

// ---------------- CSR build ----------------
__global__ void hist_kernel(const int* __restrict__ dst, int* __restrict__ deg, int E)
{
  int i = blockIdx.x * blockDim.x + threadIdx.x;
  if (i < E) atomicAdd(&deg[dst[i]], 1);
}

__global__ __launch_bounds__(1024) void exscan_kernel(const int* __restrict__ deg,
                                                      int* __restrict__ off, int n)
{
  __shared__ int wsum[16];
  __shared__ int carry_s;
  const int t = threadIdx.x, lane = t & 63, w = t >> 6;
  if (t == 0) carry_s = 0;
  __syncthreads();
  for (int base = 0; base < n; base += 1024) {
    int i = base + t;
    int v = (i < n) ? deg[i] : 0;
    int x = v;
#pragma unroll
    for (int d = 1; d < 64; d <<= 1) {
      int y = __shfl_up(x, d, 64);
      if (lane >= d) x += y;
    }
    if (lane == 63) wsum[w] = x;
    __syncthreads();
    if (w == 0) {
      int s = (lane < 16) ? wsum[lane] : 0;
#pragma unroll
      for (int d = 1; d < 16; d <<= 1) {
        int y = __shfl_up(s, d, 64);
        if (lane >= d) s += y;
      }
      if (lane < 16) wsum[lane] = s;
    }
    __syncthreads();
    int wpre = (w > 0) ? wsum[w - 1] : 0;
    int incl = carry_s + wpre + x;
    if (i < n) off[i] = incl - v;
    __syncthreads();
    if (t == 1023) carry_s = incl;
    __syncthreads();
  }
  if (t == 0) off[n] = carry_s;
}

__global__ void scatter_kernel(const int* __restrict__ src, const int* __restrict__ dst,
                               const int* __restrict__ off, int* __restrict__ cursor,
                               int* __restrict__ sidx, int* __restrict__ slotOf, int E)
{
  int i = blockIdx.x * blockDim.x + threadIdx.x;
  if (i < E) {
    int d = dst[i];
    int p = atomicAdd(&cursor[d], 1);
    int slot = off[d] + p;
    sidx[slot] = src[i];
    slotOf[i] = slot;
  }
}

// ---------------- per-node attention logits ----------------
__global__ void logits_kernel(const float* __restrict__ hW, const float* __restrict__ att_s,
                              const float* __restrict__ att_d, float* __restrict__ a_s,
                              float* __restrict__ a_d, int n_nodes)
{
  int t = blockIdx.x * blockDim.x + threadIdx.x;
  if (t >= n_nodes * HEADS) return;
  int n = t >> 2, h = t & 3;
  const float* hp = hW + (size_t)n * FDIM + h * HID;
  const float* ws = att_s + h * HID;
  const float* wd = att_d + h * HID;
  float as = 0.f, ad = 0.f;
#pragma unroll 4
  for (int k = 0; k < HID; ++k) {
    float xv = hp[k];
    as = fmaf(xv, ws[k], as);
    ad = fmaf(xv, wd[k], ad);
  }
  a_s[t] = as;
  a_d[t] = ad;
}

// ---------------- per-edge logits into CSR order ----------------
__global__ void elog_kernel(const int* __restrict__ src, const int* __restrict__ dst,
                            const int* __restrict__ slotOf,
                            const float* __restrict__ a_s, const float* __restrict__ a_d,
                            float4* __restrict__ elog, int E)
{
  int i = blockIdx.x * blockDim.x + threadIdx.x;
  if (i >= E) return;
  const float4 as = *reinterpret_cast<const float4*>(a_s + (size_t)src[i] * 4);
  const float4 ad = *reinterpret_cast<const float4*>(a_d + (size_t)dst[i] * 4);
  float4 e;
  e.x = lrelu(as.x + ad.x);
  e.y = lrelu(as.y + ad.y);
  e.z = lrelu(as.z + ad.z);
  e.w = lrelu(as.w + ad.w);
  elog[slotOf[i]] = e;
}

// ---------------- GAT aggregation: one wave per dst node; bf16 hi/lo out ----------------
__global__ __launch_bounds__(256) void aggregate_kernel(
    const float* __restrict__ hW, float* __restrict__ elog, const int* __restrict__ sidx,
    const int* __restrict__ off, const float* __restrict__ bias,
    ushort* __restrict__ outHi, ushort* __restrict__ outLo, int n_nodes)
{
  const int wid  = (blockIdx.x * 256 + threadIdx.x) >> 6;
  const int lane = threadIdx.x & 63;
  if (wid >= n_nodes) return;
  const int n = wid;
  const int beg = off[n], end = off[n + 1];

  float m = -INFINITY;
  for (int p = beg * 4 + lane; p < end * 4; p += 64) m = fmaxf(m, elog[p]);
#pragma unroll
  for (int d = 4; d < 64; d <<= 1) m = fmaxf(m, __shfl_xor(m, d, 64));
  float ssum = 0.f;
  for (int p = beg * 4 + lane; p < end * 4; p += 64) {
    float w = __expf(elog[p] - m);
    elog[p] = w;
    ssum += w;
  }
#pragma unroll
  for (int d = 4; d < 64; d <<= 1) ssum += __shfl_xor(ssum, d, 64);
  const float s0 = __shfl(ssum, 0, 64), s1 = __shfl(ssum, 1, 64);
  const float s2 = __shfl(ssum, 2, 64), s3 = __shfl(ssum, 3, 64);

  float acc0 = 0.f, acc1 = 0.f, acc2 = 0.f, acc3 = 0.f;
  const float4* wv = reinterpret_cast<const float4*>(elog);
#pragma unroll 4
  for (int j = beg; j < end; ++j) {
    const int s = sidx[j];
    const float4 w = wv[j];
    const float* hp = hW + (size_t)s * FDIM;
    acc0 = fmaf(w.x, hp[lane], acc0);
    acc1 = fmaf(w.y, hp[64 + lane], acc1);
    acc2 = fmaf(w.z, hp[128 + lane], acc2);
    acc3 = fmaf(w.w, hp[192 + lane], acc3);
  }
  float v0 = acc0 / (s0 + 1e-16f) + bias[lane];
  float v1 = acc1 / (s1 + 1e-16f) + bias[64 + lane];
  float v2 = acc2 / (s2 + 1e-16f) + bias[128 + lane];
  float v3 = acc3 / (s3 + 1e-16f) + bias[192 + lane];
  ushort* oh = outHi + (size_t)n * FDIM;
  ushort* ol = outLo + (size_t)n * FDIM;
  ushort h0 = f2bf(v0), h1 = f2bf(v1), h2 = f2bf(v2), h3 = f2bf(v3);
  oh[lane] = h0;        ol[lane]       = f2bf(v0 - bf2f(h0));
  oh[64 + lane] = h1;   ol[64 + lane]  = f2bf(v1 - bf2f(h1));
  oh[128 + lane] = h2;  ol[128 + lane] = f2bf(v2 - bf2f(h2));
  oh[192 + lane] = h3;  ol[192 + lane] = f2bf(v3 - bf2f(h3));
}

// ---------------- link predictor: one wave per eval pair ----------------
__global__ __launch_bounds__(256) void linkpred_kernel(
    const float* __restrict__ u, const float* __restrict__ v,
    const int* __restrict__ es, const int* __restrict__ ed,
    const float* __restrict__ b1, const float* __restrict__ w2, const float* __restrict__ b2,
    const float* __restrict__ w3, const float* __restrict__ b3,
    float* __restrict__ out, int n_eval)
{
  __shared__ float w2s[64 * 32];
  __shared__ float z1s[4][64];
  __shared__ float z2s[4][32];
  const int t = threadIdx.x;
  for (int i = t; i < 64 * 32; i += 256) w2s[i] = w2[i];
  const int wid = t >> 6, lane = t & 63;
  const int pair = blockIdx.x * 4 + wid;
  const bool valid = pair < n_eval;
  const int pc = valid ? pair : (n_eval - 1);
  const int s = es[pc], d = ed[pc];
  float z1 = fmaxf(u[(size_t)s * 64 + lane] + v[(size_t)d * 64 + lane] + b1[lane], 0.f);
  z1s[wid][lane] = z1;
  __syncthreads();
  if (lane < 32) {
    float acc = b2[lane];
#pragma unroll
    for (int k = 0; k < 64; ++k) acc = fmaf(z1s[wid][k], w2s[k * 32 + lane], acc);
    z2s[wid][lane] = fmaxf(acc, 0.f);
  }
  __syncthreads();
  if (lane == 0 && valid) {
    float acc = b3[0];
#pragma unroll
    for (int k = 0; k < 32; ++k) acc = fmaf(z2s[wid][k], w3[k], acc);
    out[pair] = acc;
  }
}

// ---------------- launch ----------------
extern "C" void kernel_launch(void* const* d_in, const int* in_sizes, int n_in,
                              void* d_out, int out_size, void* d_ws, size_t ws_size,
                              hipStream_t stream)
{
  const float* x     = (const float*)d_in[0];
  const int*   ei    = (const int*)d_in[1];
  const int*   esrc  = (const int*)d_in[2];
  const int*   edst  = (const int*)d_in[3];
  const float* enc_w = (const float*)d_in[4];
  const float* enc_b = (const float*)d_in[5];
  const float* g1_w  = (const float*)d_in[6];
  const float* g1_as = (const float*)d_in[7];
  const float* g1_ad = (const float*)d_in[8];
  const float* g1_b  = (const float*)d_in[9];
  const float* g2_w  = (const float*)d_in[10];
  const float* g2_as = (const float*)d_in[11];
  const float* g2_ad = (const float*)d_in[12];
  const float* g2_b  = (const float*)d_in[13];
  const float* lp1_w = (const float*)d_in[14];
  const float* lp1_b = (const float*)d_in[15];
  const float* lp2_w = (const float*)d_in[16];
  const float* lp2_b = (const float*)d_in[17];
  const float* lp3_w = (const float*)d_in[18];
  const float* lp3_b = (const float*)d_in[19];
  float* out = (float*)d_out;

  const int E  = in_sizes[1] / 2;   // 1,000,000
  const int NE = in_sizes[2];       // 100,000
  const int M  = NNODES;

  const int* e_src = ei;
  const int* e_dst = ei + E;

  // ---- workspace layout (~129 MB) ----
  float* hW    = (float*)d_ws;                         // M*256 f32
  float* a_s   = hW + (size_t)M * FDIM;                // M*4
  float* a_d   = a_s + (size_t)M * HEADS;              // M*4
  float* elogf = a_d + (size_t)M * HEADS;              // E*4 f32 (16MB)
  ushort* h_hi = (ushort*)elogf;                       // alias: M*64 bf16 (dead before elog written)
  ushort* h_lo = h_hi + (size_t)M * HID;
  ushort* agg_hi = (ushort*)(elogf + (size_t)E * 4);   // M*256 bf16 (also x_hi)
  ushort* agg_lo = agg_hi + (size_t)M * FDIM;          // (also x_lo)
  int*   deg    = (int*)(agg_lo + (size_t)M * FDIM);
  int*   cursor = deg + M;
  int*   off    = cursor + M;
  int*   sidx   = off + M + 1;
  int*   slotOf = sidx + E;
  ushort* wb     = (ushort*)(slotOf + E);
  ushort* we_hi  = wb;                 ushort* we_lo  = we_hi + 256 * 64;
  ushort* w1_hi  = we_lo + 256 * 64;   ushort* w1_lo  = w1_hi + 64 * 256;
  ushort* w2_hi  = w1_lo + 64 * 256;   ushort* w2_lo  = w2_hi + 256 * 256;
  ushort* wu_hi  = w2_lo + 256 * 256;  ushort* wu_lo  = wu_hi + 256 * 64;
  ushort* wv_hi  = wu_lo + 256 * 64;   ushort* wv_lo  = wv_hi + 256 * 64;
  ushort* x_hi = agg_hi;   // x planes dead after encoder; agg written later
  ushort* x_lo = agg_lo;
  float* u = hW;           // hW dead after aggregate2
  float* v = hW + (size_t)M * HID;

  // ---- CSR build ----
  hipMemsetAsync(deg, 0, sizeof(int) * 2 * (size_t)M, stream);
  hist_kernel<<<(E + 255) / 256, 256, 0, stream>>>(e_dst, deg, E);
  exscan_kernel<<<1, 1024, 0, stream>>>(deg, off, M);
  scatter_kernel<<<(E + 255) / 256, 256, 0, stream>>>(e_src, e_dst, off, cursor, sidx, slotOf, E);

  // ---- input & weight conversions ----
  {
    int n4 = M * FDIM / 4;
    split_kernel<<<(n4 + 255) / 256, 256, 0, stream>>>((const float4*)x, x_hi, x_lo, n4);
    wtconv_kernel<<<(256 * 64 + 255) / 256, 256, 0, stream>>>(enc_w, we_hi, we_lo, 256, 64);
    wtconv_kernel<<<(64 * 256 + 255) / 256, 256, 0, stream>>>(g1_w, w1_hi, w1_lo, 64, 256);
    wtconv_kernel<<<(256 * 256 + 255) / 256, 256, 0, stream>>>(g2_w, w2_hi, w2_lo, 256, 256);
    wtconv_kernel<<<(256 * 64 + 255) / 256, 256, 0, stream>>>(lp1_w, wu_hi, wu_lo, 256, 64);
    wtconv_kernel<<<(256 * 64 + 255) / 256, 256, 0, stream>>>(lp1_w + 256 * 64, wv_hi, wv_lo, 256, 64);
  }

  const int GB = (M + 127) / 128;   // 391 row-blocks

  // ---- encoder: h = relu(x @ enc_w + b), split bf16 out ----
  mfma_gemm<256, 1><<<dim3(GB, 1), 256, 0, stream>>>(
      x_hi, x_lo, we_hi, we_lo, enc_b, nullptr, h_hi, h_lo, M, HID);

  // ---- GAT layer 1 ----
  mfma_gemm<64, 0><<<dim3(GB, 4), 256, 0, stream>>>(
      h_hi, h_lo, w1_hi, w1_lo, nullptr, hW, nullptr, nullptr, M, FDIM);
  logits_kernel<<<(M * HEADS + 255) / 256, 256, 0, stream>>>(hW, g1_as, g1_ad, a_s, a_d, M);
  elog_kernel<<<(E + 255) / 256, 256, 0, stream>>>(e_src, e_dst, slotOf, a_s, a_d, (float4*)elogf, E);
  aggregate_kernel<<<(M * 64 + 255) / 256, 256, 0, stream>>>(hW, elogf, sidx, off, g1_b, agg_hi, agg_lo, M);

  // ---- GAT layer 2 ----
  mfma_gemm<256, 0><<<dim3(GB, 4), 256, 0, stream>>>(
      agg_hi, agg_lo, w2_hi, w2_lo, nullptr, hW, nullptr, nullptr, M, FDIM);
  logits_kernel<<<(M * HEADS + 255) / 256, 256, 0, stream>>>(hW, g2_as, g2_ad, a_s, a_d, M);
  elog_kernel<<<(E + 255) / 256, 256, 0, stream>>>(e_src, e_dst, slotOf, a_s, a_d, (float4*)elogf, E);
  aggregate_kernel<<<(M * 64 + 255) / 256, 256, 0, stream>>>(hW, elogf, sidx, off, g2_b, agg_hi, agg_lo, M);

  // ---- link predictor ----
  mfma_gemm<256, 0><<<dim3(GB, 1), 256, 0, stream>>>(
      agg_hi, agg_lo, wu_hi, wu_lo, nullptr, u, nullptr, nullptr, M, HID);
  mfma_gemm<256, 0><<<dim3(GB, 1), 256, 0, stream>>>(
      agg_hi, agg_lo, wv_hi, wv_lo, nullptr, v, nullptr, nullptr, M, HID);
  linkpred_kernel<<<(NE + 3) / 4, 256, 0, stream>>>(u, v, esrc, edst, lp1_b, lp2_w, lp2_b,
                                                    lp3_w, lp3_b, out, NE);
}

// Round 4
// 711.566 us; speedup vs baseline: 1.8815x; 1.2570x over previous
//
#include <hip/hip_runtime.h>
#include <hip/hip_bf16.h>
#include <math.h>

#define NNODES 50000
#define HID    64
#define HEADS  4
#define FDIM   256   // HEADS*HID

typedef __attribute__((ext_vector_type(8))) short short8v;
typedef __attribute__((ext_vector_type(4))) float f32x4;

__device__ __forceinline__ float lrelu(float x) { return x > 0.f ? x : 0.2f * x; }

__device__ __forceinline__ ushort f2bf(float x) {
  union { float f; unsigned u; } c; c.f = x;
  unsigned r = (c.u + 0x7FFF + ((c.u >> 16) & 1)) >> 16;   // RNE
  return (ushort)r;
}
__device__ __forceinline__ float bf2f(ushort h) {
  union { unsigned u; float f; } c; c.u = ((unsigned)h) << 16;
  return c.f;
}

// ---------------- f32 -> (hi,lo) bf16 split, vectorized ----------------
__global__ void split_kernel(const float4* __restrict__ x, ushort* __restrict__ hi,
                             ushort* __restrict__ lo, int n4)
{
  int t = blockIdx.x * blockDim.x + threadIdx.x;
  if (t >= n4) return;
  float4 v = x[t];
  ushort h0 = f2bf(v.x), h1 = f2bf(v.y), h2 = f2bf(v.z), h3 = f2bf(v.w);
  *(ushort4*)(hi + (size_t)t * 4) = make_ushort4(h0, h1, h2, h3);
  *(ushort4*)(lo + (size_t)t * 4) = make_ushort4(
      f2bf(v.x - bf2f(h0)), f2bf(v.y - bf2f(h1)),
      f2bf(v.z - bf2f(h2)), f2bf(v.w - bf2f(h3)));
}

// ---------------- W[K][N] f32 -> Wt_hi/Wt_lo [N][K] bf16 ----------------
__global__ void wtconv_kernel(const float* __restrict__ W, ushort* __restrict__ Whi,
                              ushort* __restrict__ Wlo, int K, int N)
{
  int t = blockIdx.x * blockDim.x + threadIdx.x;
  if (t >= K * N) return;
  int n = t / K, k = t - n * K;
  float w = W[(size_t)k * N + n];
  ushort h = f2bf(w);
  Whi[t] = h;
  Wlo[t] = f2bf(w - bf2f(h));
}

// ---------------- MFMA GEMM: C[M,Ntot] = A[M,KTOT] @ B, 3-pass bf16 ----------------
// OUTMODE 0: f32 out. OUTMODE 1: bias+relu, split hi/lo bf16. OUTMODE 2: plain bf16.
template<int KTOT, int OUTMODE>
__global__ __launch_bounds__(256) void mfma_gemm(
    const ushort* __restrict__ Ahi, const ushort* __restrict__ Alo,
    const ushort* __restrict__ Bhi, const ushort* __restrict__ Blo,
    const float* __restrict__ bias,
    float* __restrict__ outF, ushort* __restrict__ outHi, ushort* __restrict__ outLo,
    int M, int Ntot)
{
  __shared__ ushort AsH[128 * 64];
  __shared__ ushort AsL[128 * 64];
  const int tid  = threadIdx.x;
  const int lane = tid & 63;
  const int wid  = tid >> 6;
  const int row0 = blockIdx.x * 128;
  const int col0 = blockIdx.y * 64;

  f32x4 acc[2][4];
#pragma unroll
  for (int m = 0; m < 2; ++m)
#pragma unroll
    for (int n = 0; n < 4; ++n) acc[m][n] = (f32x4){0.f, 0.f, 0.f, 0.f};

  const int rsub = lane >> 3;   // row within 8-row chunk
  const int slot = lane & 7;    // 16B slot within 128B LDS row
  const int brow = col0 + (lane & 15);
  const int bk   = (lane >> 4) * 8;

  for (int kt = 0; kt < KTOT; kt += 64) {
#pragma unroll
    for (int i = 0; i < 4; ++i) {
      const int c  = i * 4 + wid;
      const int r  = c * 8 + rsub;
      const int gr = min(row0 + r, M - 1);
      const int ss = slot ^ rsub;                       // involution swizzle (T2)
      const size_t goff = (size_t)gr * KTOT + kt + ss * 8;
      __builtin_amdgcn_global_load_lds(
          (const __attribute__((address_space(1))) void*)(Ahi + goff),
          (__attribute__((address_space(3))) void*)(AsH + c * 512), 16, 0, 0);
      __builtin_amdgcn_global_load_lds(
          (const __attribute__((address_space(1))) void*)(Alo + goff),
          (__attribute__((address_space(3))) void*)(AsL + c * 512), 16, 0, 0);
    }
    __syncthreads();

#pragma unroll
    for (int ks = 0; ks < 2; ++ks) {
      short8v ah[2], al[2], bh[4], bl[4];
#pragma unroll
      for (int mf = 0; mf < 2; ++mf) {
        const int r   = wid * 32 + mf * 16 + (lane & 15);
        const int sl  = (ks * 4 + (lane >> 4)) ^ (r & 7);
        const int idx = r * 64 + sl * 8;
        ah[mf] = *(const short8v*)(AsH + idx);
        al[mf] = *(const short8v*)(AsL + idx);
      }
#pragma unroll
      for (int nf = 0; nf < 4; ++nf) {
        const size_t bo = (size_t)(brow + nf * 16) * KTOT + kt + ks * 32 + bk;
        bh[nf] = *(const short8v*)(Bhi + bo);
        bl[nf] = *(const short8v*)(Blo + bo);
      }
#pragma unroll
      for (int mf = 0; mf < 2; ++mf)
#pragma unroll
        for (int nf = 0; nf < 4; ++nf) {
          acc[mf][nf] = __builtin_amdgcn_mfma_f32_16x16x32_bf16(ah[mf], bh[nf], acc[mf][nf], 0, 0, 0);
          acc[mf][nf] = __builtin_amdgcn_mfma_f32_16x16x32_bf16(al[mf], bh[nf], acc[mf][nf], 0, 0, 0);
          acc[mf][nf] = __builtin_amdgcn_mfma_f32_16x16x32_bf16(ah[mf], bl[nf], acc[mf][nf], 0, 0, 0);
        }
    }
    __syncthreads();
  }

  const int crow = row0 + wid * 32 + (lane >> 4) * 4;
  const int ccol = col0 + (lane & 15);
#pragma unroll
  for (int mf = 0; mf < 2; ++mf)
#pragma unroll
    for (int nf = 0; nf < 4; ++nf)
#pragma unroll
      for (int r = 0; r < 4; ++r) {
        const int grow = crow + mf * 16 + r;
        const int gcol = ccol + nf * 16;
        if (grow < M) {
          float v = acc[mf][nf][r];
          if (OUTMODE == 0) {
            outF[(size_t)grow * Ntot + gcol] = v;
          } else if (OUTMODE == 1) {
            v = fmaxf(v + bias[gcol], 0.f);
            const ushort h = f2bf(v);
            outHi[(size_t)grow * Ntot + gcol] = h;
            outLo[(size_t)grow * Ntot + gcol] = f2bf(v - bf2f(h));
          } else {
            outHi[(size_t)grow * Ntot + gcol] = f2bf(v);
          }
        }
      }
}

// ---------------- CSR build ----------------
__global__ void hist_kernel(const int* __restrict__ dst, int* __restrict__ deg, int E)
{
  int i = blockIdx.x * blockDim.x + threadIdx.x;
  if (i < E) atomicAdd(&deg[dst[i]], 1);
}

__global__ __launch_bounds__(1024) void exscan_kernel(const int* __restrict__ deg,
                                                      int* __restrict__ off, int n)
{
  __shared__ int wsum[16];
  __shared__ int carry_s;
  const int t = threadIdx.x, lane = t & 63, w = t >> 6;
  if (t == 0) carry_s = 0;
  __syncthreads();
  for (int base = 0; base < n; base += 1024) {
    int i = base + t;
    int v = (i < n) ? deg[i] : 0;
    int x = v;
#pragma unroll
    for (int d = 1; d < 64; d <<= 1) {
      int y = __shfl_up(x, d, 64);
      if (lane >= d) x += y;
    }
    if (lane == 63) wsum[w] = x;
    __syncthreads();
    if (w == 0) {
      int s = (lane < 16) ? wsum[lane] : 0;
#pragma unroll
      for (int d = 1; d < 16; d <<= 1) {
        int y = __shfl_up(s, d, 64);
        if (lane >= d) s += y;
      }
      if (lane < 16) wsum[lane] = s;
    }
    __syncthreads();
    int wpre = (w > 0) ? wsum[w - 1] : 0;
    int incl = carry_s + wpre + x;
    if (i < n) off[i] = incl - v;
    __syncthreads();
    if (t == 1023) carry_s = incl;
    __syncthreads();
  }
  if (t == 0) off[n] = carry_s;
}

__global__ void scatter_kernel(const int* __restrict__ src, const int* __restrict__ dst,
                               const int* __restrict__ off, int* __restrict__ cursor,
                               int* __restrict__ sidx, int E)
{
  int i = blockIdx.x * blockDim.x + threadIdx.x;
  if (i < E) {
    int d = dst[i];
    int p = atomicAdd(&cursor[d], 1);
    sidx[off[d] + p] = src[i];
  }
}

// ---------------- per-node attention logits from bf16 h ----------------
__global__ void logits_kernel(const ushort* __restrict__ hWb, const float* __restrict__ att_s,
                              const float* __restrict__ att_d, float* __restrict__ a_s,
                              float* __restrict__ a_d, int n_nodes)
{
  int t = blockIdx.x * blockDim.x + threadIdx.x;
  if (t >= n_nodes * HEADS) return;
  int n = t >> 2, h = t & 3;
  const ushort* hp = hWb + (size_t)n * FDIM + h * HID;
  const float* ws = att_s + h * HID;
  const float* wd = att_d + h * HID;
  float as = 0.f, ad = 0.f;
#pragma unroll
  for (int k = 0; k < HID; k += 4) {
    ushort4 hv = *(const ushort4*)(hp + k);
    float x0 = bf2f(hv.x), x1 = bf2f(hv.y), x2 = bf2f(hv.z), x3 = bf2f(hv.w);
    as = fmaf(x0, ws[k], as);     ad = fmaf(x0, wd[k], ad);
    as = fmaf(x1, ws[k + 1], as); ad = fmaf(x1, wd[k + 1], ad);
    as = fmaf(x2, ws[k + 2], as); ad = fmaf(x2, wd[k + 2], ad);
    as = fmaf(x3, ws[k + 3], as); ad = fmaf(x3, wd[k + 3], ad);
  }
  a_s[t] = as;
  a_d[t] = ad;
}

// ---------------- GAT aggregation v3: one wave per dst node ----------------
// Phase A: gather a_s[src] per flat (edge,head), online softmax (m,s), write raw e.
// Phase B: per edge, w = exp(e - m_head); bf16 message gather (512B/edge), f32 accum.
__global__ __launch_bounds__(256) void aggregate_kernel(
    const ushort* __restrict__ hWb, float* __restrict__ elog, const int* __restrict__ sidx,
    const int* __restrict__ off, const float* __restrict__ a_s, const float* __restrict__ a_d,
    const float* __restrict__ bias,
    ushort* __restrict__ outHi, ushort* __restrict__ outLo, int n_nodes)
{
  const int wid  = (blockIdx.x * 256 + threadIdx.x) >> 6;
  const int lane = threadIdx.x & 63;
  if (wid >= n_nodes) return;
  const int n = wid;
  const int beg = off[n], end = off[n + 1];

  // ---- Phase A ----
  const int hsel = lane & 3;
  const float adh = a_d[n * 4 + hsel];
  float m = -1e30f, ssum = 0.f;
  for (int p = beg * 4 + lane; p < end * 4; p += 64) {
    const int s = sidx[p >> 2];
    const float e = lrelu(a_s[s * 4 + hsel] + adh);
    elog[p] = e;
    const float mn = fmaxf(m, e);
    ssum = ssum * __expf(m - mn) + __expf(e - mn);
    m = mn;
  }
#pragma unroll
  for (int d = 4; d < 64; d <<= 1) {
    const float mo = __shfl_xor(m, d, 64);
    const float so = __shfl_xor(ssum, d, 64);
    const float mn = fmaxf(m, mo);
    ssum = ssum * __expf(m - mn) + so * __expf(mo - mn);
    m = mn;
  }
  const int hb = lane >> 4;                   // head this lane accumulates in phase B
  const float mh = __shfl(m, hb, 64);         // lane hb holds head hb's stats
  const float sh = __shfl(ssum, hb, 64);

  // ---- Phase B ----
  float acc0 = 0.f, acc1 = 0.f, acc2 = 0.f, acc3 = 0.f;
#pragma unroll 4
  for (int j = beg; j < end; ++j) {
    const int s = sidx[j];
    const float e = elog[j * 4 + hb];
    const float w = __expf(e - mh);
    const ushort4 hv = *(const ushort4*)(hWb + (size_t)s * FDIM + lane * 4);
    acc0 = fmaf(w, bf2f(hv.x), acc0);
    acc1 = fmaf(w, bf2f(hv.y), acc1);
    acc2 = fmaf(w, bf2f(hv.z), acc2);
    acc3 = fmaf(w, bf2f(hv.w), acc3);
  }
  const float inv = 1.f / (sh + 1e-16f);
  const int c = lane * 4;
  const float4 bv = *(const float4*)(bias + c);
  const float v0 = acc0 * inv + bv.x;
  const float v1 = acc1 * inv + bv.y;
  const float v2 = acc2 * inv + bv.z;
  const float v3 = acc3 * inv + bv.w;
  const ushort h0 = f2bf(v0), h1 = f2bf(v1), h2 = f2bf(v2), h3 = f2bf(v3);
  *(ushort4*)(outHi + (size_t)n * FDIM + c) = make_ushort4(h0, h1, h2, h3);
  *(ushort4*)(outLo + (size_t)n * FDIM + c) = make_ushort4(
      f2bf(v0 - bf2f(h0)), f2bf(v1 - bf2f(h1)),
      f2bf(v2 - bf2f(h2)), f2bf(v3 - bf2f(h3)));
}

// ---------------- link predictor: one wave per eval pair ----------------
__global__ __launch_bounds__(256) void linkpred_kernel(
    const float* __restrict__ u, const float* __restrict__ v,
    const int* __restrict__ es, const int* __restrict__ ed,
    const float* __restrict__ b1, const float* __restrict__ w2, const float* __restrict__ b2,
    const float* __restrict__ w3, const float* __restrict__ b3,
    float* __restrict__ out, int n_eval)
{
  __shared__ float w2s[64 * 32];
  __shared__ float z1s[4][64];
  __shared__ float z2s[4][32];
  const int t = threadIdx.x;
  for (int i = t; i < 64 * 32; i += 256) w2s[i] = w2[i];
  const int wid = t >> 6, lane = t & 63;
  const int pair = blockIdx.x * 4 + wid;
  const bool valid = pair < n_eval;
  const int pc = valid ? pair : (n_eval - 1);
  const int s = es[pc], d = ed[pc];
  float z1 = fmaxf(u[(size_t)s * 64 + lane] + v[(size_t)d * 64 + lane] + b1[lane], 0.f);
  z1s[wid][lane] = z1;
  __syncthreads();
  if (lane < 32) {
    float acc = b2[lane];
#pragma unroll
    for (int k = 0; k < 64; ++k) acc = fmaf(z1s[wid][k], w2s[k * 32 + lane], acc);
    z2s[wid][lane] = fmaxf(acc, 0.f);
  }
  __syncthreads();
  if (lane == 0 && valid) {
    float acc = b3[0];
#pragma unroll
    for (int k = 0; k < 32; ++k) acc = fmaf(z2s[wid][k], w3[k], acc);
    out[pair] = acc;
  }
}

// ---------------- launch ----------------
extern "C" void kernel_launch(void* const* d_in, const int* in_sizes, int n_in,
                              void* d_out, int out_size, void* d_ws, size_t ws_size,
                              hipStream_t stream)
{
  const float* x     = (const float*)d_in[0];
  const int*   ei    = (const int*)d_in[1];
  const int*   esrc  = (const int*)d_in[2];
  const int*   edst  = (const int*)d_in[3];
  const float* enc_w = (const float*)d_in[4];
  const float* enc_b = (const float*)d_in[5];
  const float* g1_w  = (const float*)d_in[6];
  const float* g1_as = (const float*)d_in[7];
  const float* g1_ad = (const float*)d_in[8];
  const float* g1_b  = (const float*)d_in[9];
  const float* g2_w  = (const float*)d_in[10];
  const float* g2_as = (const float*)d_in[11];
  const float* g2_ad = (const float*)d_in[12];
  const float* g2_b  = (const float*)d_in[13];
  const float* lp1_w = (const float*)d_in[14];
  const float* lp1_b = (const float*)d_in[15];
  const float* lp2_w = (const float*)d_in[16];
  const float* lp2_b = (const float*)d_in[17];
  const float* lp3_w = (const float*)d_in[18];
  const float* lp3_b = (const float*)d_in[19];
  float* out = (float*)d_out;

  const int E  = in_sizes[1] / 2;   // 1,000,000
  const int NE = in_sizes[2];       // 100,000
  const int M  = NNODES;

  const int* e_src = ei;
  const int* e_dst = ei + E;

  // ---- workspace layout (~100 MB) ----
  ushort* hWb  = (ushort*)d_ws;                        // M*256 bf16 = 25.6MB
  float* a_s   = (float*)(hWb + (size_t)M * FDIM);     // M*4
  float* a_d   = a_s + (size_t)M * HEADS;              // M*4
  float* elogf = a_d + (size_t)M * HEADS;              // E*4 f32 = 16MB
  ushort* h_hi = (ushort*)elogf;                       // alias: M*64 bf16 (dead before elog use)
  ushort* h_lo = h_hi + (size_t)M * HID;
  ushort* agg_hi = (ushort*)(elogf + (size_t)E * 4);   // M*256 bf16 (also x_hi)
  ushort* agg_lo = agg_hi + (size_t)M * FDIM;          // (also x_lo)
  int*   deg    = (int*)(agg_lo + (size_t)M * FDIM);
  int*   cursor = deg + M;
  int*   off    = cursor + M;
  int*   sidx   = off + M + 1;
  ushort* wb     = (ushort*)(sidx + E);
  ushort* we_hi  = wb;                 ushort* we_lo  = we_hi + 256 * 64;
  ushort* w1_hi  = we_lo + 256 * 64;   ushort* w1_lo  = w1_hi + 64 * 256;
  ushort* w2_hi  = w1_lo + 64 * 256;   ushort* w2_lo  = w2_hi + 256 * 256;
  ushort* wu_hi  = w2_lo + 256 * 256;  ushort* wu_lo  = wu_hi + 256 * 64;
  ushort* wv_hi  = wu_lo + 256 * 64;   ushort* wv_lo  = wv_hi + 256 * 64;
  ushort* x_hi = agg_hi;   // x planes dead after encoder; agg written later
  ushort* x_lo = agg_lo;
  float* u = (float*)hWb;  // hWb dead after aggregate2
  float* v = u + (size_t)M * HID;

  // ---- CSR build ----
  hipMemsetAsync(deg, 0, sizeof(int) * 2 * (size_t)M, stream);
  hist_kernel<<<(E + 255) / 256, 256, 0, stream>>>(e_dst, deg, E);
  exscan_kernel<<<1, 1024, 0, stream>>>(deg, off, M);
  scatter_kernel<<<(E + 255) / 256, 256, 0, stream>>>(e_src, e_dst, off, cursor, sidx, E);

  // ---- input & weight conversions ----
  {
    int n4 = M * FDIM / 4;
    split_kernel<<<(n4 + 255) / 256, 256, 0, stream>>>((const float4*)x, x_hi, x_lo, n4);
    wtconv_kernel<<<(256 * 64 + 255) / 256, 256, 0, stream>>>(enc_w, we_hi, we_lo, 256, 64);
    wtconv_kernel<<<(64 * 256 + 255) / 256, 256, 0, stream>>>(g1_w, w1_hi, w1_lo, 64, 256);
    wtconv_kernel<<<(256 * 256 + 255) / 256, 256, 0, stream>>>(g2_w, w2_hi, w2_lo, 256, 256);
    wtconv_kernel<<<(256 * 64 + 255) / 256, 256, 0, stream>>>(lp1_w, wu_hi, wu_lo, 256, 64);
    wtconv_kernel<<<(256 * 64 + 255) / 256, 256, 0, stream>>>(lp1_w + 256 * 64, wv_hi, wv_lo, 256, 64);
  }

  const int GB = (M + 127) / 128;   // 391 row-blocks

  // ---- encoder: h = relu(x @ enc_w + b), split bf16 out ----
  mfma_gemm<256, 1><<<dim3(GB, 1), 256, 0, stream>>>(
      x_hi, x_lo, we_hi, we_lo, enc_b, nullptr, h_hi, h_lo, M, HID);

  // ---- GAT layer 1 ----
  mfma_gemm<64, 2><<<dim3(GB, 4), 256, 0, stream>>>(
      h_hi, h_lo, w1_hi, w1_lo, nullptr, nullptr, hWb, nullptr, M, FDIM);
  logits_kernel<<<(M * HEADS + 255) / 256, 256, 0, stream>>>(hWb, g1_as, g1_ad, a_s, a_d, M);
  aggregate_kernel<<<(M * 64 + 255) / 256, 256, 0, stream>>>(
      hWb, elogf, sidx, off, a_s, a_d, g1_b, agg_hi, agg_lo, M);

  // ---- GAT layer 2 ----
  mfma_gemm<256, 2><<<dim3(GB, 4), 256, 0, stream>>>(
      agg_hi, agg_lo, w2_hi, w2_lo, nullptr, nullptr, hWb, nullptr, M, FDIM);
  logits_kernel<<<(M * HEADS + 255) / 256, 256, 0, stream>>>(hWb, g2_as, g2_ad, a_s, a_d, M);
  aggregate_kernel<<<(M * 64 + 255) / 256, 256, 0, stream>>>(
      hWb, elogf, sidx, off, a_s, a_d, g2_b, agg_hi, agg_lo, M);

  // ---- link predictor ----
  mfma_gemm<256, 0><<<dim3(GB, 1), 256, 0, stream>>>(
      agg_hi, agg_lo, wu_hi, wu_lo, nullptr, u, nullptr, nullptr, M, HID);
  mfma_gemm<256, 0><<<dim3(GB, 1), 256, 0, stream>>>(
      agg_hi, agg_lo, wv_hi, wv_lo, nullptr, v, nullptr, nullptr, M, HID);
  linkpred_kernel<<<(NE + 3) / 4, 256, 0, stream>>>(u, v, esrc, edst, lp1_b, lp2_w, lp2_b,
                                                    lp3_w, lp3_b, out, NE);
}

// Round 5
// 661.110 us; speedup vs baseline: 2.0250x; 1.0763x over previous
//
#include <hip/hip_runtime.h>
#include <hip/hip_bf16.h>
#include <math.h>

#define NNODES 50000
#define HID    64
#define HEADS  4
#define FDIM   256   // HEADS*HID

typedef __attribute__((ext_vector_type(8))) short short8v;
typedef __attribute__((ext_vector_type(4))) float f32x4;

__device__ __forceinline__ float lrelu(float x) { return x > 0.f ? x : 0.2f * x; }

__device__ __forceinline__ ushort f2bf(float x) {
  union { float f; unsigned u; } c; c.f = x;
  unsigned r = (c.u + 0x7FFF + ((c.u >> 16) & 1)) >> 16;   // RNE
  return (ushort)r;
}
__device__ __forceinline__ float bf2f(ushort h) {
  union { unsigned u; float f; } c; c.u = ((unsigned)h) << 16;
  return c.f;
}

// ---------------- f32 -> (hi,lo) bf16 split, vectorized ----------------
__global__ void split_kernel(const float4* __restrict__ x, ushort* __restrict__ hi,
                             ushort* __restrict__ lo, int n4)
{
  int t = blockIdx.x * blockDim.x + threadIdx.x;
  if (t >= n4) return;
  float4 v = x[t];
  ushort h0 = f2bf(v.x), h1 = f2bf(v.y), h2 = f2bf(v.z), h3 = f2bf(v.w);
  *(ushort4*)(hi + (size_t)t * 4) = make_ushort4(h0, h1, h2, h3);
  *(ushort4*)(lo + (size_t)t * 4) = make_ushort4(
      f2bf(v.x - bf2f(h0)), f2bf(v.y - bf2f(h1)),
      f2bf(v.z - bf2f(h2)), f2bf(v.w - bf2f(h3)));
}

// ---------------- all weight transposes+splits in ONE kernel ----------------
// enc: [256,64]->we[64][256]; g1: [64,256]->w1[256][64]; g2: [256,256]->w2[256][256];
// lp1: [512,64] -> wlp[128][256] (rows 0-63 = u-part, 64-127 = v-part)
__global__ void wtconv_all_kernel(const float* __restrict__ enc_w, const float* __restrict__ g1_w,
                                  const float* __restrict__ g2_w, const float* __restrict__ lp1_w,
                                  ushort* __restrict__ we_hi, ushort* __restrict__ we_lo,
                                  ushort* __restrict__ w1_hi, ushort* __restrict__ w1_lo,
                                  ushort* __restrict__ w2_hi, ushort* __restrict__ w2_lo,
                                  ushort* __restrict__ wlp_hi, ushort* __restrict__ wlp_lo)
{
  int t = blockIdx.x * blockDim.x + threadIdx.x;   // 0..131071
  float w; ushort* dh; ushort* dl; int di;
  if (t < 16384) {                       // enc: N=64,K=256
    int n = t >> 8, k = t & 255;
    w = enc_w[(size_t)k * 64 + n]; dh = we_hi; dl = we_lo; di = t;
  } else if (t < 32768) {                // g1: N=256,K=64
    int l = t - 16384; int n = l >> 6, k = l & 63;
    w = g1_w[(size_t)k * 256 + n]; dh = w1_hi; dl = w1_lo; di = l;
  } else if (t < 98304) {                // g2: N=256,K=256
    int l = t - 32768; int n = l >> 8, k = l & 255;
    w = g2_w[(size_t)k * 256 + n]; dh = w2_hi; dl = w2_lo; di = l;
  } else {                               // lp stacked: N=128,K=256
    int l = t - 98304; int n = l >> 8, k = l & 255;
    int srow = (n < 64) ? k : (256 + k);
    w = lp1_w[(size_t)srow * 64 + (n & 63)]; dh = wlp_hi; dl = wlp_lo; di = l;
  }
  ushort h = f2bf(w);
  dh[di] = h;
  dl[di] = f2bf(w - bf2f(h));
}

// ---------------- MFMA GEMM: C[M,Ntot] = A[M,KTOT] @ B, 3-pass bf16 ----------------
// OUTMODE 0: f32 out. OUTMODE 1: bias+relu, split hi/lo bf16. OUTMODE 2: plain bf16.
template<int KTOT, int OUTMODE>
__global__ __launch_bounds__(256) void mfma_gemm(
    const ushort* __restrict__ Ahi, const ushort* __restrict__ Alo,
    const ushort* __restrict__ Bhi, const ushort* __restrict__ Blo,
    const float* __restrict__ bias,
    float* __restrict__ outF, ushort* __restrict__ outHi, ushort* __restrict__ outLo,
    int M, int Ntot)
{
  __shared__ ushort AsH[128 * 64];
  __shared__ ushort AsL[128 * 64];
  const int tid  = threadIdx.x;
  const int lane = tid & 63;
  const int wid  = tid >> 6;
  const int row0 = blockIdx.x * 128;
  const int col0 = blockIdx.y * 64;

  f32x4 acc[2][4];
#pragma unroll
  for (int m = 0; m < 2; ++m)
#pragma unroll
    for (int n = 0; n < 4; ++n) acc[m][n] = (f32x4){0.f, 0.f, 0.f, 0.f};

  const int rsub = lane >> 3;   // row within 8-row chunk
  const int slot = lane & 7;    // 16B slot within 128B LDS row
  const int brow = col0 + (lane & 15);
  const int bk   = (lane >> 4) * 8;

  for (int kt = 0; kt < KTOT; kt += 64) {
#pragma unroll
    for (int i = 0; i < 4; ++i) {
      const int c  = i * 4 + wid;
      const int r  = c * 8 + rsub;
      const int gr = min(row0 + r, M - 1);
      const int ss = slot ^ rsub;                       // involution swizzle (T2)
      const size_t goff = (size_t)gr * KTOT + kt + ss * 8;
      __builtin_amdgcn_global_load_lds(
          (const __attribute__((address_space(1))) void*)(Ahi + goff),
          (__attribute__((address_space(3))) void*)(AsH + c * 512), 16, 0, 0);
      __builtin_amdgcn_global_load_lds(
          (const __attribute__((address_space(1))) void*)(Alo + goff),
          (__attribute__((address_space(3))) void*)(AsL + c * 512), 16, 0, 0);
    }
    __syncthreads();

#pragma unroll
    for (int ks = 0; ks < 2; ++ks) {
      short8v ah[2], al[2], bh[4], bl[4];
#pragma unroll
      for (int mf = 0; mf < 2; ++mf) {
        const int r   = wid * 32 + mf * 16 + (lane & 15);
        const int sl  = (ks * 4 + (lane >> 4)) ^ (r & 7);
        const int idx = r * 64 + sl * 8;
        ah[mf] = *(const short8v*)(AsH + idx);
        al[mf] = *(const short8v*)(AsL + idx);
      }
#pragma unroll
      for (int nf = 0; nf < 4; ++nf) {
        const size_t bo = (size_t)(brow + nf * 16) * KTOT + kt + ks * 32 + bk;
        bh[nf] = *(const short8v*)(Bhi + bo);
        bl[nf] = *(const short8v*)(Blo + bo);
      }
#pragma unroll
      for (int mf = 0; mf < 2; ++mf)
#pragma unroll
        for (int nf = 0; nf < 4; ++nf) {
          acc[mf][nf] = __builtin_amdgcn_mfma_f32_16x16x32_bf16(ah[mf], bh[nf], acc[mf][nf], 0, 0, 0);
          acc[mf][nf] = __builtin_amdgcn_mfma_f32_16x16x32_bf16(al[mf], bh[nf], acc[mf][nf], 0, 0, 0);
          acc[mf][nf] = __builtin_amdgcn_mfma_f32_16x16x32_bf16(ah[mf], bl[nf], acc[mf][nf], 0, 0, 0);
        }
    }
    __syncthreads();
  }

  const int crow = row0 + wid * 32 + (lane >> 4) * 4;
  const int ccol = col0 + (lane & 15);
#pragma unroll
  for (int mf = 0; mf < 2; ++mf)
#pragma unroll
    for (int nf = 0; nf < 4; ++nf)
#pragma unroll
      for (int r = 0; r < 4; ++r) {
        const int grow = crow + mf * 16 + r;
        const int gcol = ccol + nf * 16;
        if (grow < M) {
          float v = acc[mf][nf][r];
          if (OUTMODE == 0) {
            outF[(size_t)grow * Ntot + gcol] = v;
          } else if (OUTMODE == 1) {
            v = fmaxf(v + bias[gcol], 0.f);
            const ushort h = f2bf(v);
            outHi[(size_t)grow * Ntot + gcol] = h;
            outLo[(size_t)grow * Ntot + gcol] = f2bf(v - bf2f(h));
          } else {
            outHi[(size_t)grow * Ntot + gcol] = f2bf(v);
          }
        }
      }
}

// ---------------- CSR build ----------------
__global__ void hist_kernel(const int* __restrict__ dst, int* __restrict__ deg, int E)
{
  int i = blockIdx.x * blockDim.x + threadIdx.x;
  if (i < E) atomicAdd(&deg[dst[i]], 1);
}

// 3-kernel parallel exclusive scan over deg[0..n)
__global__ void scan1_kernel(const int* __restrict__ deg, int* __restrict__ off,
                             int* __restrict__ bsum, int n)
{
  __shared__ int ws[4];
  const int t = threadIdx.x, lane = t & 63, w = t >> 6;
  const int i = blockIdx.x * 256 + t;
  const int v = (i < n) ? deg[i] : 0;
  int x = v;
#pragma unroll
  for (int d = 1; d < 64; d <<= 1) {
    int y = __shfl_up(x, d, 64);
    if (lane >= d) x += y;
  }
  if (lane == 63) ws[w] = x;
  __syncthreads();
  int add = 0;
  for (int k = 0; k < w; ++k) add += ws[k];
  if (i < n) off[i] = add + x - v;
  if (t == 255) bsum[blockIdx.x] = add + x;
}

__global__ void scan2_kernel(int* __restrict__ bsum, int nb)
{
  __shared__ int ws[4];
  const int t = threadIdx.x, lane = t & 63, w = t >> 6;
  const int v = (t < nb) ? bsum[t] : 0;
  int x = v;
#pragma unroll
  for (int d = 1; d < 64; d <<= 1) {
    int y = __shfl_up(x, d, 64);
    if (lane >= d) x += y;
  }
  if (lane == 63) ws[w] = x;
  __syncthreads();
  int add = 0;
  for (int k = 0; k < w; ++k) add += ws[k];
  if (t < nb) bsum[t] = add + x - v;
}

__global__ void scan3_kernel(int* __restrict__ off, const int* __restrict__ bsum, int n, int E)
{
  const int i = blockIdx.x * 256 + threadIdx.x;
  if (i < n) off[i] += bsum[blockIdx.x];
  if (i == 0) off[n] = E;
}

__global__ void scatter_kernel(const int* __restrict__ src, const int* __restrict__ dst,
                               const int* __restrict__ off, int* __restrict__ cursor,
                               int* __restrict__ sidx, int E)
{
  int i = blockIdx.x * blockDim.x + threadIdx.x;
  if (i < E) {
    int d = dst[i];
    int p = atomicAdd(&cursor[d], 1);
    sidx[off[d] + p] = src[i];
  }
}

// ---------------- per-node attention logits from bf16 h ----------------
__global__ void logits_kernel(const ushort* __restrict__ hWb, const float* __restrict__ att_s,
                              const float* __restrict__ att_d, float* __restrict__ a_s,
                              float* __restrict__ a_d, int n_nodes)
{
  int t = blockIdx.x * blockDim.x + threadIdx.x;
  if (t >= n_nodes * HEADS) return;
  int n = t >> 2, h = t & 3;
  const ushort* hp = hWb + (size_t)n * FDIM + h * HID;
  const float* ws = att_s + h * HID;
  const float* wd = att_d + h * HID;
  float as = 0.f, ad = 0.f;
#pragma unroll
  for (int k = 0; k < HID; k += 4) {
    ushort4 hv = *(const ushort4*)(hp + k);
    float x0 = bf2f(hv.x), x1 = bf2f(hv.y), x2 = bf2f(hv.z), x3 = bf2f(hv.w);
    as = fmaf(x0, ws[k], as);     ad = fmaf(x0, wd[k], ad);
    as = fmaf(x1, ws[k + 1], as); ad = fmaf(x1, wd[k + 1], ad);
    as = fmaf(x2, ws[k + 2], as); ad = fmaf(x2, wd[k + 2], ad);
    as = fmaf(x3, ws[k + 3], as); ad = fmaf(x3, wd[k + 3], ad);
  }
  a_s[t] = as;
  a_d[t] = ad;
}

// ---------------- GAT aggregation v4: one wave per dst node, no elog ----------------
// Phase A: gather a_s[src] per flat (edge,head), online softmax (m,s) only.
// Phase B: recompute e from a_s (L2-hot), w = exp(e-m); bf16 message gather.
__global__ __launch_bounds__(256) void aggregate_kernel(
    const ushort* __restrict__ hWb, const int* __restrict__ sidx,
    const int* __restrict__ off, const float* __restrict__ a_s, const float* __restrict__ a_d,
    const float* __restrict__ bias,
    ushort* __restrict__ outHi, ushort* __restrict__ outLo, int n_nodes)
{
  const int wid  = (blockIdx.x * 256 + threadIdx.x) >> 6;
  const int lane = threadIdx.x & 63;
  if (wid >= n_nodes) return;
  const int n = wid;
  const int beg = off[n], end = off[n + 1];

  // ---- Phase A ----
  const int hsel = lane & 3;
  const float adh = a_d[n * 4 + hsel];
  float m = -1e30f, ssum = 0.f;
  for (int p = beg * 4 + lane; p < end * 4; p += 64) {
    const int s = sidx[p >> 2];
    const float e = lrelu(a_s[s * 4 + hsel] + adh);
    const float mn = fmaxf(m, e);
    ssum = ssum * __expf(m - mn) + __expf(e - mn);
    m = mn;
  }
#pragma unroll
  for (int d = 4; d < 64; d <<= 1) {
    const float mo = __shfl_xor(m, d, 64);
    const float so = __shfl_xor(ssum, d, 64);
    const float mn = fmaxf(m, mo);
    ssum = ssum * __expf(m - mn) + so * __expf(mo - mn);
    m = mn;
  }
  const int hb = lane >> 4;                   // head this lane accumulates in phase B
  const float mh    = __shfl(m, hb, 64);
  const float sh    = __shfl(ssum, hb, 64);
  const float adh_b = __shfl(adh, hb, 64);    // a_d[n*4+hb]

  // ---- Phase B ----
  float acc0 = 0.f, acc1 = 0.f, acc2 = 0.f, acc3 = 0.f;
#pragma unroll 4
  for (int j = beg; j < end; ++j) {
    const int s = sidx[j];
    const float e = lrelu(a_s[s * 4 + hb] + adh_b);
    const float w = __expf(e - mh);
    const ushort4 hv = *(const ushort4*)(hWb + (size_t)s * FDIM + lane * 4);
    acc0 = fmaf(w, bf2f(hv.x), acc0);
    acc1 = fmaf(w, bf2f(hv.y), acc1);
    acc2 = fmaf(w, bf2f(hv.z), acc2);
    acc3 = fmaf(w, bf2f(hv.w), acc3);
  }
  const float inv = 1.f / (sh + 1e-16f);
  const int c = lane * 4;
  const float4 bv = *(const float4*)(bias + c);
  const float v0 = acc0 * inv + bv.x;
  const float v1 = acc1 * inv + bv.y;
  const float v2 = acc2 * inv + bv.z;
  const float v3 = acc3 * inv + bv.w;
  const ushort h0 = f2bf(v0), h1 = f2bf(v1), h2 = f2bf(v2), h3 = f2bf(v3);
  *(ushort4*)(outHi + (size_t)n * FDIM + c) = make_ushort4(h0, h1, h2, h3);
  *(ushort4*)(outLo + (size_t)n * FDIM + c) = make_ushort4(
      f2bf(v0 - bf2f(h0)), f2bf(v1 - bf2f(h1)),
      f2bf(v2 - bf2f(h2)), f2bf(v3 - bf2f(h3)));
}

// ---------------- link predictor: one wave per eval pair; uv interleaved [n][128] ----------------
__global__ __launch_bounds__(256) void linkpred_kernel(
    const float* __restrict__ uv,
    const int* __restrict__ es, const int* __restrict__ ed,
    const float* __restrict__ b1, const float* __restrict__ w2, const float* __restrict__ b2,
    const float* __restrict__ w3, const float* __restrict__ b3,
    float* __restrict__ out, int n_eval)
{
  __shared__ float w2s[64 * 32];
  __shared__ float z1s[4][64];
  __shared__ float z2s[4][32];
  const int t = threadIdx.x;
  for (int i = t; i < 64 * 32; i += 256) w2s[i] = w2[i];
  const int wid = t >> 6, lane = t & 63;
  const int pair = blockIdx.x * 4 + wid;
  const bool valid = pair < n_eval;
  const int pc = valid ? pair : (n_eval - 1);
  const int s = es[pc], d = ed[pc];
  float z1 = fmaxf(uv[(size_t)s * 128 + lane] + uv[(size_t)d * 128 + 64 + lane] + b1[lane], 0.f);
  z1s[wid][lane] = z1;
  __syncthreads();
  if (lane < 32) {
    float acc = b2[lane];
#pragma unroll
    for (int k = 0; k < 64; ++k) acc = fmaf(z1s[wid][k], w2s[k * 32 + lane], acc);
    z2s[wid][lane] = fmaxf(acc, 0.f);
  }
  __syncthreads();
  if (lane == 0 && valid) {
    float acc = b3[0];
#pragma unroll
    for (int k = 0; k < 32; ++k) acc = fmaf(z2s[wid][k], w3[k], acc);
    out[pair] = acc;
  }
}

// ---------------- launch ----------------
extern "C" void kernel_launch(void* const* d_in, const int* in_sizes, int n_in,
                              void* d_out, int out_size, void* d_ws, size_t ws_size,
                              hipStream_t stream)
{
  const float* x     = (const float*)d_in[0];
  const int*   ei    = (const int*)d_in[1];
  const int*   esrc  = (const int*)d_in[2];
  const int*   edst  = (const int*)d_in[3];
  const float* enc_w = (const float*)d_in[4];
  const float* enc_b = (const float*)d_in[5];
  const float* g1_w  = (const float*)d_in[6];
  const float* g1_as = (const float*)d_in[7];
  const float* g1_ad = (const float*)d_in[8];
  const float* g1_b  = (const float*)d_in[9];
  const float* g2_w  = (const float*)d_in[10];
  const float* g2_as = (const float*)d_in[11];
  const float* g2_ad = (const float*)d_in[12];
  const float* g2_b  = (const float*)d_in[13];
  const float* lp1_w = (const float*)d_in[14];
  const float* lp1_b = (const float*)d_in[15];
  const float* lp2_w = (const float*)d_in[16];
  const float* lp2_b = (const float*)d_in[17];
  const float* lp3_w = (const float*)d_in[18];
  const float* lp3_b = (const float*)d_in[19];
  float* out = (float*)d_out;

  const int E  = in_sizes[1] / 2;   // 1,000,000
  const int NE = in_sizes[2];       // 100,000
  const int M  = NNODES;
  const int NB = (M + 255) / 256;   // scan blocks = 196

  const int* e_src = ei;
  const int* e_dst = ei + E;

  // ---- workspace layout (~97 MB) ----
  ushort* hWb  = (ushort*)d_ws;                        // M*256 bf16 = 25.6MB (aliased by uv later)
  float* a_s   = (float*)(hWb + (size_t)M * FDIM);     // M*4
  float* a_d   = a_s + (size_t)M * HEADS;              // M*4
  ushort* h_hi = (ushort*)(a_d + (size_t)M * HEADS);   // M*64 bf16
  ushort* h_lo = h_hi + (size_t)M * HID;
  ushort* agg_hi = h_lo + (size_t)M * HID;             // M*256 bf16 (also x_hi)
  ushort* agg_lo = agg_hi + (size_t)M * FDIM;          // (also x_lo)
  int*   deg    = (int*)(agg_lo + (size_t)M * FDIM);
  int*   cursor = deg + M;
  int*   off    = cursor + M;
  int*   bsum   = off + M + 1;                         // NB ints
  int*   sidx   = bsum + 256;
  ushort* wb     = (ushort*)(sidx + E);
  ushort* we_hi  = wb;                  ushort* we_lo  = we_hi + 256 * 64;
  ushort* w1_hi  = we_lo + 256 * 64;    ushort* w1_lo  = w1_hi + 64 * 256;
  ushort* w2_hi  = w1_lo + 64 * 256;    ushort* w2_lo  = w2_hi + 256 * 256;
  ushort* wlp_hi = w2_lo + 256 * 256;   ushort* wlp_lo = wlp_hi + 128 * 256;
  ushort* x_hi = agg_hi;   // x planes dead after encoder; agg written later
  ushort* x_lo = agg_lo;
  float* uv = (float*)hWb; // hWb dead after aggregate2; uv = M*128 f32 = 25.6MB

  // ---- CSR build ----
  hipMemsetAsync(deg, 0, sizeof(int) * 2 * (size_t)M, stream);
  hist_kernel<<<(E + 255) / 256, 256, 0, stream>>>(e_dst, deg, E);
  scan1_kernel<<<NB, 256, 0, stream>>>(deg, off, bsum, M);
  scan2_kernel<<<1, 256, 0, stream>>>(bsum, NB);
  scan3_kernel<<<NB, 256, 0, stream>>>(off, bsum, M, E);
  scatter_kernel<<<(E + 255) / 256, 256, 0, stream>>>(e_src, e_dst, off, cursor, sidx, E);

  // ---- input & weight conversions ----
  {
    int n4 = M * FDIM / 4;
    split_kernel<<<(n4 + 255) / 256, 256, 0, stream>>>((const float4*)x, x_hi, x_lo, n4);
    wtconv_all_kernel<<<512, 256, 0, stream>>>(enc_w, g1_w, g2_w, lp1_w,
                                               we_hi, we_lo, w1_hi, w1_lo,
                                               w2_hi, w2_lo, wlp_hi, wlp_lo);
  }

  const int GB = (M + 127) / 128;   // 391 row-blocks

  // ---- encoder: h = relu(x @ enc_w + b), split bf16 out ----
  mfma_gemm<256, 1><<<dim3(GB, 1), 256, 0, stream>>>(
      x_hi, x_lo, we_hi, we_lo, enc_b, nullptr, h_hi, h_lo, M, HID);

  // ---- GAT layer 1 ----
  mfma_gemm<64, 2><<<dim3(GB, 4), 256, 0, stream>>>(
      h_hi, h_lo, w1_hi, w1_lo, nullptr, nullptr, hWb, nullptr, M, FDIM);
  logits_kernel<<<(M * HEADS + 255) / 256, 256, 0, stream>>>(hWb, g1_as, g1_ad, a_s, a_d, M);
  aggregate_kernel<<<(M * 64 + 255) / 256, 256, 0, stream>>>(
      hWb, sidx, off, a_s, a_d, g1_b, agg_hi, agg_lo, M);

  // ---- GAT layer 2 ----
  mfma_gemm<256, 2><<<dim3(GB, 4), 256, 0, stream>>>(
      agg_hi, agg_lo, w2_hi, w2_lo, nullptr, nullptr, hWb, nullptr, M, FDIM);
  logits_kernel<<<(M * HEADS + 255) / 256, 256, 0, stream>>>(hWb, g2_as, g2_ad, a_s, a_d, M);
  aggregate_kernel<<<(M * 64 + 255) / 256, 256, 0, stream>>>(
      hWb, sidx, off, a_s, a_d, g2_b, agg_hi, agg_lo, M);

  // ---- link predictor: one fused GEMM (u|v stacked), then pair MLP ----
  mfma_gemm<256, 0><<<dim3(GB, 2), 256, 0, stream>>>(
      agg_hi, agg_lo, wlp_hi, wlp_lo, nullptr, uv, nullptr, nullptr, M, 2 * HID);
  linkpred_kernel<<<(NE + 3) / 4, 256, 0, stream>>>(uv, esrc, edst, lp1_b, lp2_w, lp2_b,
                                                    lp3_w, lp3_b, out, NE);
}